// Round 1
// baseline (288.402 us; speedup 1.0000x reference)
//
#include <hip/hip_runtime.h>

// Problem: x (B=8, C=3, T=32, H=256, W=256) fp32 ->
//   grayscale (0.2989, 0.587, 0.114) over C ->
//   8x8 non-overlapping blocks -> 2D DCT-II (norm=None): out = D @ G @ D^T
//   out shape (B, T, 1024, 8, 8) fp32, flat out_size = 16,777,216
//
// Memory-bound: 201 MB read + 67 MB write => ~43 us at 6.3 TB/s achievable.
//
// One workgroup (256 thr) per (b, t, block-row of 8 pixel rows):
//   grid = B*T*(H/8) = 8192 workgroups.

#define TPB 256

__global__ __launch_bounds__(TPB) void dct_gray_kernel(
    const float* __restrict__ x, float* __restrict__ out) {
  constexpr int T = 32, H = 256, W = 256;
  __shared__ float g[8][256];   // 8 KB grayscale strip
  __shared__ float Dm[64];      // DCT matrix D[k][n]

  const int wg  = blockIdx.x;   // 0..8191
  const int tid = threadIdx.x;
  const int bt  = wg >> 5;      // b*T + t   (H/8 = 32 block-rows)
  const int hb  = wg & 31;      // block-row index

  // Build D[k][n] = 2*cos(pi*(2n+1)*k/16) once (64 lanes)
  if (tid < 64) {
    const int k = tid >> 3, n = tid & 7;
    Dm[tid] = 2.0f * cosf(0.19634954084936207f * (float)((2 * n + 1) * k));
  }

  const int b = bt >> 5;   // / T
  const int t = bt & 31;
  const size_t cstride = (size_t)T * H * W;                     // channel stride
  const size_t base0 =
      ((size_t)(b * 3) * T + (size_t)t) * (size_t)(H * W) + (size_t)hb * 8 * W;

  const float w0 = 0.2989f, w1 = 0.587f, w2 = 0.114f;

  // Stage 1: coalesced float4 loads of 3 channels, fuse grayscale, stash in LDS.
  // 8 rows * 64 float4 = 512 float4 -> 2 iterations of 256 threads.
#pragma unroll
  for (int i = tid; i < 512; i += TPB) {
    const int r  = i >> 6;      // row within strip
    const int c4 = i & 63;      // float4 column
    const size_t off = base0 + (size_t)r * W + (size_t)(c4 * 4);
    const float4 a = *(const float4*)(x + off);
    const float4 bb = *(const float4*)(x + off + cstride);
    const float4 cc = *(const float4*)(x + off + 2 * cstride);
    float4 gg;
    gg.x = w0 * a.x + w1 * bb.x + w2 * cc.x;
    gg.y = w0 * a.y + w1 * bb.y + w2 * cc.y;
    gg.z = w0 * a.z + w1 * bb.z + w2 * cc.z;
    gg.w = w0 * a.w + w1 * bb.w + w2 * cc.w;
    *(float4*)(&g[r][c4 * 4]) = gg;
  }
  __syncthreads();

  // Stage 2: thread tid -> block p = tid>>3 (0..31), output row k = tid&7.
  // temp[m] = sum_n D[k][n] * g[n][p*8+m];  res[l] = sum_m temp[m]*D[l][m].
  const int p = tid >> 3;
  const int k = tid & 7;

  float temp[8];
#pragma unroll
  for (int m = 0; m < 8; ++m) temp[m] = 0.0f;
#pragma unroll
  for (int n = 0; n < 8; ++n) {
    const float dkn = Dm[k * 8 + n];
    const float4 g0 = *(const float4*)(&g[n][p * 8]);      // ds_read_b128
    const float4 g1 = *(const float4*)(&g[n][p * 8 + 4]);  // 2-way alias: free
    temp[0] += dkn * g0.x; temp[1] += dkn * g0.y;
    temp[2] += dkn * g0.z; temp[3] += dkn * g0.w;
    temp[4] += dkn * g1.x; temp[5] += dkn * g1.y;
    temp[6] += dkn * g1.z; temp[7] += dkn * g1.w;
  }

  float res[8];
#pragma unroll
  for (int l = 0; l < 8; ++l) {
    float acc = 0.0f;
#pragma unroll
    for (int m = 0; m < 8; ++m) acc += temp[m] * Dm[l * 8 + m];
    res[l] = acc;
  }

  // Output: workgroup owns 2048 contiguous floats at wg*2048; thread writes
  // 8 consecutive floats at tid*8 (p*64 + k*8).
  float* o = out + (size_t)wg * 2048 + (size_t)tid * 8;
  *(float4*)(o)     = make_float4(res[0], res[1], res[2], res[3]);
  *(float4*)(o + 4) = make_float4(res[4], res[5], res[6], res[7]);
}

extern "C" void kernel_launch(void* const* d_in, const int* in_sizes, int n_in,
                              void* d_out, int out_size, void* d_ws, size_t ws_size,
                              hipStream_t stream) {
  const float* x = (const float*)d_in[0];
  float* out = (float*)d_out;
  // grid = B*T*(H/8) = 8*32*32 = 8192
  dct_gray_kernel<<<8192, TPB, 0, stream>>>(x, out);
}